// Round 7
// baseline (570.067 us; speedup 1.0000x reference)
//
#include <hip/hip_runtime.h>

#define NN 100000
#define EE 1600000
#define TOT (EE + NN)
#define NEG 0.2f
#define GEMM_BLKS ((NN + 63) / 64)      // 1563

typedef unsigned int uint;
typedef unsigned short ushort;
typedef unsigned char uchar;

__device__ inline ushort f2bf(float f) {            // RNE f32 -> bf16
    uint u = __float_as_uint(f);
    return (ushort)((u + 0x7fff + ((u >> 16) & 1)) >> 16);
}

__device__ inline int imin(int a, int b) { return a < b ? a : b; }

// ---------------- CSR build ----------------

// histogram + within-node rank; 4 edges/thread, overlapped returning atomics
__global__ void k_hist(const int* __restrict__ dst, int* counts, uchar* rank) {
    int e0 = (blockIdx.x * 256 + threadIdx.x) * 4;   // EE % 4 == 0: full quads
    if (e0 >= EE) return;
    int4 d4 = *(const int4*)(dst + e0);
    int r0 = atomicAdd(&counts[d4.x], 1);
    int r1 = atomicAdd(&counts[d4.y], 1);
    int r2 = atomicAdd(&counts[d4.z], 1);
    int r3 = atomicAdd(&counts[d4.w], 1);
    *(uchar4*)(rank + e0) = make_uchar4((uchar)r0, (uchar)r1, (uchar)r2, (uchar)r3);
}

__global__ void k_scan1(const int* __restrict__ counts, int* row_off, int* partial) {
    __shared__ int sm[256];
    int i = blockIdx.x * 256 + threadIdx.x;
    int v = (i < NN) ? counts[i] + 1 : 0;   // +1 = self-loop
    sm[threadIdx.x] = v;
    __syncthreads();
    for (int off = 1; off < 256; off <<= 1) {
        int t = (threadIdx.x >= off) ? sm[threadIdx.x - off] : 0;
        __syncthreads();
        sm[threadIdx.x] += t;
        __syncthreads();
    }
    if (i < NN) row_off[i] = sm[threadIdx.x] - v;   // exclusive
    if (threadIdx.x == 255) partial[blockIdx.x] = sm[255];
}

__global__ void k_scan2(int* partial, int nb) {
    __shared__ int sm[512];
    int t = threadIdx.x;
    int v = (t < nb) ? partial[t] : 0;
    sm[t] = v;
    __syncthreads();
    for (int off = 1; off < 512; off <<= 1) {
        int x = (t >= off) ? sm[t - off] : 0;
        __syncthreads();
        sm[t] += x;
        __syncthreads();
    }
    if (t < nb) partial[t] = sm[t] - v;             // exclusive
}

__global__ void k_scan3(int* row_off, const int* __restrict__ partial) {
    int i = blockIdx.x * 256 + threadIdx.x;
    if (i < NN) row_off[i] += partial[blockIdx.x];
    if (i == 0) row_off[NN] = TOT;
}

// atomic-free fill, 4 edges/thread: vectorized edge loads (coalesced), then
// 4 independent row_off gathers in flight, then 4 independent 8B nt stores.
__global__ void k_fill(const int* __restrict__ src, const int* __restrict__ dst,
                       const float* __restrict__ ew, const int* __restrict__ row_off,
                       const int* __restrict__ counts, const uchar* __restrict__ rank,
                       long long* __restrict__ csr) {
    int e0 = (blockIdx.x * 256 + threadIdx.x) * 4;   // TOT % 4 == 0, EE % 4 == 0
    if (e0 >= TOT) return;
    long long rec[4];
    int pos[4];
    if (e0 < EE) {
        int4   d4 = *(const int4*)(dst + e0);
        int4   s4 = *(const int4*)(src + e0);
        float4 w4 = *(const float4*)(ew + e0);
        uchar4 r4 = *(const uchar4*)(rank + e0);
        pos[0] = row_off[d4.x] + r4.x;
        pos[1] = row_off[d4.y] + r4.y;
        pos[2] = row_off[d4.z] + r4.z;
        pos[3] = row_off[d4.w] + r4.w;
        rec[0] = (long long)(uint)s4.x | ((long long)__float_as_uint(w4.x) << 32);
        rec[1] = (long long)(uint)s4.y | ((long long)__float_as_uint(w4.y) << 32);
        rec[2] = (long long)(uint)s4.z | ((long long)__float_as_uint(w4.z) << 32);
        rec[3] = (long long)(uint)s4.w | ((long long)__float_as_uint(w4.w) << 32);
    } else {
        int n0 = e0 - EE;                            // 4 sequential self-loops
#pragma unroll
        for (int j = 0; j < 4; ++j) {
            int node = n0 + j;
            pos[j] = row_off[node] + counts[node];
            rec[j] = (long long)(uint)node | (0x3f800000LL << 32);  // w = 1.0f
        }
    }
#pragma unroll
    for (int j = 0; j < 4; ++j)
        __builtin_nontemporal_store(rec[j], csr + pos[j]);
}

// ---------------- GEMM1: xp16 = bf16(x @ Wg), + a_s/a_d logit epilogue -------
// wave = 64 rows x 32 cols; W addresses wave-uniform -> scalar loads.

__launch_bounds__(256) __global__
void k_gemm1(const float* __restrict__ A, const float* __restrict__ W,
             ushort* __restrict__ C16,
             const float* __restrict__ att_s, const float* __restrict__ att_d,
             float* __restrict__ a_s, float* __restrict__ a_d) {
    int lane = threadIdx.x & 63;
    int cg = __builtin_amdgcn_readfirstlane(threadIdx.x >> 6);  // 0..3
    int row = blockIdx.x * 64 + lane;
    bool valid = row < NN;
    if (!valid) row = NN - 1;
    const float* __restrict__ a = A + (size_t)row * 128;
    const float* __restrict__ w = W + cg * 32;
    float acc[32];
#pragma unroll
    for (int c = 0; c < 32; ++c) acc[c] = 0.f;
    for (int k = 0; k < 128; k += 4) {
        float4 xv = *(const float4*)(a + k);
        float xs[4] = {xv.x, xv.y, xv.z, xv.w};
#pragma unroll
        for (int kk = 0; kk < 4; ++kk) {
            const float* wr = w + (k + kk) * 128;
            float xk = xs[kk];
#pragma unroll
            for (int c = 0; c < 32; ++c) acc[c] = fmaf(xk, wr[c], acc[c]);
        }
    }
    if (valid) {
        ushort* o = C16 + (size_t)row * 128 + cg * 32;
#pragma unroll
        for (int c = 0; c < 32; c += 8) {
            uint4 p;
            p.x = (uint)f2bf(acc[c+0]) | ((uint)f2bf(acc[c+1]) << 16);
            p.y = (uint)f2bf(acc[c+2]) | ((uint)f2bf(acc[c+3]) << 16);
            p.z = (uint)f2bf(acc[c+4]) | ((uint)f2bf(acc[c+5]) << 16);
            p.w = (uint)f2bf(acc[c+6]) | ((uint)f2bf(acc[c+7]) << 16);
            *(uint4*)(o + c) = p;
        }
        const float* as = att_s + cg * 32;
        const float* ad = att_d + cg * 32;
        float s0 = 0.f, s1 = 0.f;
#pragma unroll
        for (int c = 0; c < 32; ++c) {
            s0 = fmaf(acc[c], as[c], s0);
            s1 = fmaf(acc[c], ad[c], s1);
        }
        a_s[row * 4 + cg] = s0;
        a_d[row * 4 + cg] = s1;
    }
}

// ---------------- GEMM2: h16 = bf16((ygat @ Wc) * dinv[row]) -----------------

__launch_bounds__(256) __global__
void k_gemm2(const float* __restrict__ A, const float* __restrict__ W,
             ushort* __restrict__ C16, const float* __restrict__ dscale) {
    int lane = threadIdx.x & 63;
    int cg = __builtin_amdgcn_readfirstlane(threadIdx.x >> 6);
    int row = blockIdx.x * 64 + lane;
    bool valid = row < NN;
    if (!valid) row = NN - 1;
    const float* __restrict__ a = A + (size_t)row * 128;
    const float* __restrict__ w = W + cg * 32;
    float acc[32];
#pragma unroll
    for (int c = 0; c < 32; ++c) acc[c] = 0.f;
    for (int k = 0; k < 128; k += 4) {
        float4 xv = *(const float4*)(a + k);
        float xs[4] = {xv.x, xv.y, xv.z, xv.w};
#pragma unroll
        for (int kk = 0; kk < 4; ++kk) {
            const float* wr = w + (k + kk) * 128;
            float xk = xs[kk];
#pragma unroll
            for (int c = 0; c < 32; ++c) acc[c] = fmaf(xk, wr[c], acc[c]);
        }
    }
    if (valid) {
        float sc = dscale[row];                 // fold dinv[src] into the row
        ushort* o = C16 + (size_t)row * 128 + cg * 32;
#pragma unroll
        for (int c = 0; c < 32; c += 8) {
            uint4 p;
            p.x = (uint)f2bf(acc[c+0]*sc) | ((uint)f2bf(acc[c+1]*sc) << 16);
            p.y = (uint)f2bf(acc[c+2]*sc) | ((uint)f2bf(acc[c+3]*sc) << 16);
            p.z = (uint)f2bf(acc[c+4]*sc) | ((uint)f2bf(acc[c+5]*sc) << 16);
            p.w = (uint)f2bf(acc[c+6]*sc) | ((uint)f2bf(acc[c+7]*sc) << 16);
            *(uint4*)(o + c) = p;
        }
    }
}

// ---------------- GAT aggregation: SINGLE PASS, wave per node ----------------
// No max-shift => numerator, denominator (Σ exp) and weighted degree all
// accumulate in one edge sweep; divide at write time.
// 16-lane group x 2 edges in flight, csr index prefetched one trip ahead.

__launch_bounds__(256) __global__
void k_gat(const int* __restrict__ row_off, const int2* __restrict__ csr,
           const float* __restrict__ a_s, const float* __restrict__ a_d,
           const ushort* __restrict__ xp16,
           float* __restrict__ ygat, float* __restrict__ dinv) {
    int lane = threadIdx.x & 63;
    int node = blockIdx.x * 4 + (threadIdx.x >> 6);   // NN % 4 == 0
    int base = row_off[node], end = row_off[node + 1];
    int grp = lane >> 4, sl = lane & 15, h2 = sl >> 2;
    float adh = a_d[node * 4 + h2];
    float acc[8];
#pragma unroll
    for (int j = 0; j < 8; ++j) acc[j] = 0.f;
    float den = 0.f, wsum = 0.f;
    int na = end - 1;
    int i0 = base + grp;
    int2 eA = csr[imin(i0, na)];
    int2 eB = csr[imin(i0 + 4, na)];
    for (int i = i0; i < end; i += 8) {
        int2 eA2 = csr[imin(i + 8,  na)];           // prefetch next trip
        int2 eB2 = csr[imin(i + 12, na)];
        uint4 qA = *(const uint4*)(xp16 + (size_t)eA.x * 128 + sl * 8);
        uint4 qB = *(const uint4*)(xp16 + (size_t)eB.x * 128 + sl * 8);
        float alA = a_s[eA.x * 4 + h2] + adh;
        alA = alA > 0.f ? alA : NEG * alA;
        float awA = __expf(alA);
        float awB = 0.f, wB = 0.f;
        if (i + 4 < end) {
            float alB = a_s[eB.x * 4 + h2] + adh;
            alB = alB > 0.f ? alB : NEG * alB;
            awB = __expf(alB);
            wB = __int_as_float(eB.y);
        }
        den  += awA + awB;
        wsum += __int_as_float(eA.y) + wB;
        acc[0] = fmaf(awA, __uint_as_float(qA.x << 16),         fmaf(awB, __uint_as_float(qB.x << 16),         acc[0]));
        acc[1] = fmaf(awA, __uint_as_float(qA.x & 0xffff0000u), fmaf(awB, __uint_as_float(qB.x & 0xffff0000u), acc[1]));
        acc[2] = fmaf(awA, __uint_as_float(qA.y << 16),         fmaf(awB, __uint_as_float(qB.y << 16),         acc[2]));
        acc[3] = fmaf(awA, __uint_as_float(qA.y & 0xffff0000u), fmaf(awB, __uint_as_float(qB.y & 0xffff0000u), acc[3]));
        acc[4] = fmaf(awA, __uint_as_float(qA.z << 16),         fmaf(awB, __uint_as_float(qB.z << 16),         acc[4]));
        acc[5] = fmaf(awA, __uint_as_float(qA.z & 0xffff0000u), fmaf(awB, __uint_as_float(qB.z & 0xffff0000u), acc[5]));
        acc[6] = fmaf(awA, __uint_as_float(qA.w << 16),         fmaf(awB, __uint_as_float(qB.w << 16),         acc[6]));
        acc[7] = fmaf(awA, __uint_as_float(qA.w & 0xffff0000u), fmaf(awB, __uint_as_float(qB.w & 0xffff0000u), acc[7]));
        eA = eA2; eB = eB2;
    }
#pragma unroll
    for (int j = 0; j < 8; ++j) {
        acc[j] += __shfl_xor(acc[j], 16);
        acc[j] += __shfl_xor(acc[j], 32);
    }
    den  += __shfl_xor(den, 16);   den  += __shfl_xor(den, 32);
    wsum += __shfl_xor(wsum, 16);  wsum += __shfl_xor(wsum, 32);
    if (grp == 0) {
        float il = 1.f / den;
        float* o = ygat + (size_t)node * 128 + sl * 8;
        *(float4*)(o)     = make_float4(acc[0]*il, acc[1]*il, acc[2]*il, acc[3]*il);
        *(float4*)(o + 4) = make_float4(acc[4]*il, acc[5]*il, acc[6]*il, acc[7]*il);
        if (sl == 0) dinv[node] = rsqrtf(wsum);
    }
}

// ---------------- GCN aggregation (dinv[src] pre-folded into h16) ----------

__launch_bounds__(256) __global__
void k_gcn(const int* __restrict__ row_off, const int2* __restrict__ csr,
           const float* __restrict__ dinv, const ushort* __restrict__ h16,
           float* __restrict__ out) {
    int lane = threadIdx.x & 63;
    int node = blockIdx.x * 4 + (threadIdx.x >> 6);
    int base = row_off[node], end = row_off[node + 1];
    float dn = dinv[node];
    int grp = lane >> 4, sl = lane & 15;
    float acc[8];
#pragma unroll
    for (int j = 0; j < 8; ++j) acc[j] = 0.f;
    int na = end - 1;
    int i0 = base + grp;
    int2 eA = csr[imin(i0, na)];
    int2 eB = csr[imin(i0 + 4, na)];
    for (int i = i0; i < end; i += 8) {
        int2 eA2 = csr[imin(i + 8,  na)];
        int2 eB2 = csr[imin(i + 12, na)];
        uint4 qA = *(const uint4*)(h16 + (size_t)eA.x * 128 + sl * 8);
        uint4 qB = *(const uint4*)(h16 + (size_t)eB.x * 128 + sl * 8);
        float cA = __int_as_float(eA.y) * dn;       // dinv[s] already in h16
        float cB = (i + 4 < end) ? __int_as_float(eB.y) * dn : 0.f;
        acc[0] = fmaf(cA, __uint_as_float(qA.x << 16),         fmaf(cB, __uint_as_float(qB.x << 16),         acc[0]));
        acc[1] = fmaf(cA, __uint_as_float(qA.x & 0xffff0000u), fmaf(cB, __uint_as_float(qB.x & 0xffff0000u), acc[1]));
        acc[2] = fmaf(cA, __uint_as_float(qA.y << 16),         fmaf(cB, __uint_as_float(qB.y << 16),         acc[2]));
        acc[3] = fmaf(cA, __uint_as_float(qA.y & 0xffff0000u), fmaf(cB, __uint_as_float(qB.y & 0xffff0000u), acc[3]));
        acc[4] = fmaf(cA, __uint_as_float(qA.z << 16),         fmaf(cB, __uint_as_float(qB.z << 16),         acc[4]));
        acc[5] = fmaf(cA, __uint_as_float(qA.z & 0xffff0000u), fmaf(cB, __uint_as_float(qB.z & 0xffff0000u), acc[5]));
        acc[6] = fmaf(cA, __uint_as_float(qA.w << 16),         fmaf(cB, __uint_as_float(qB.w << 16),         acc[6]));
        acc[7] = fmaf(cA, __uint_as_float(qA.w & 0xffff0000u), fmaf(cB, __uint_as_float(qB.w & 0xffff0000u), acc[7]));
        eA = eA2; eB = eB2;
    }
#pragma unroll
    for (int j = 0; j < 8; ++j) {
        acc[j] += __shfl_xor(acc[j], 16);
        acc[j] += __shfl_xor(acc[j], 32);
    }
    if (grp == 0) {
        float* o = out + (size_t)node * 128 + sl * 8;
        *(float4*)(o)     = make_float4(acc[0], acc[1], acc[2], acc[3]);
        *(float4*)(o + 4) = make_float4(acc[4], acc[5], acc[6], acc[7]);
    }
}

// ---------------- launch ----------------

extern "C" void kernel_launch(void* const* d_in, const int* in_sizes, int n_in,
                              void* d_out, int out_size, void* d_ws, size_t ws_size,
                              hipStream_t stream) {
    const float* x    = (const float*)d_in[0];
    const int*   ei   = (const int*)  d_in[1];   // [2,E]: src then dst
    const float* ew   = (const float*)d_in[2];
    const float* Wg   = (const float*)d_in[3];
    const float* atts = (const float*)d_in[4];
    const float* attd = (const float*)d_in[5];
    const float* Wc   = (const float*)d_in[6];
    float* out = (float*)d_out;

    float* ygat  = (float*)d_ws;            // 12.8M f32
    float* a_s   = ygat + 12800000;         // 400000
    float* a_d   = a_s + 400000;            // 400000
    float* dinvp = a_d + 400000;            // 100000
    int* row_off = (int*)(dinvp + 100000);  // 100004
    int* counts  = row_off + 100004;        // 100000
    int* partial = counts + 100000;         // 1024
    long long* csr = (long long*)(partial + 1024);  // 1.7M x 8B
    ushort* xp16 = (ushort*)(csr + 1700000);        // 12.8M bf16
    ushort* h16  = xp16 + 12800000;                 // 12.8M bf16
    uchar* rank  = (uchar*)h16;   // alias: rank dead before gemm2 writes h16

    const int* srcv = ei;
    const int* dstv = ei + EE;

    hipMemsetAsync(counts, 0, NN * sizeof(int), stream);
    k_hist <<<(EE / 4 + 255) / 256, 256, 0, stream>>>(dstv, counts, rank);
    k_scan1<<<391, 256, 0, stream>>>(counts, row_off, partial);
    k_scan2<<<1, 512, 0, stream>>>(partial, 391);
    k_scan3<<<391, 256, 0, stream>>>(row_off, partial);
    k_fill <<<(TOT / 4 + 255) / 256, 256, 0, stream>>>(srcv, dstv, ew, row_off,
                                                       counts, rank, csr);
    k_gemm1<<<GEMM_BLKS, 256, 0, stream>>>(x, Wg, xp16, atts, attd, a_s, a_d);
    k_gat  <<<NN / 4, 256, 0, stream>>>(row_off, (const int2*)csr, a_s, a_d, xp16,
                                        ygat, dinvp);
    k_gemm2<<<GEMM_BLKS, 256, 0, stream>>>(ygat, Wc, h16, dinvp);
    k_gcn  <<<NN / 4, 256, 0, stream>>>(row_off, (const int2*)csr, dinvp, h16, out);
}